// Round 8
// baseline (2253.285 us; speedup 1.0000x reference)
//
#include <hip/hip_runtime.h>

#define MM 2048
#define NN 2048
#define DD 64
#define NDIAG (MM + NN - 1)      /* 4095 cost-matrix anti-diagonals */
#define TOTCELLS (MM * NN)
#define MAXSEG 15

// ---- skewed-pipeline DP geometry ----
#define NWGD   4                 /* workgroups (each holds fwd+bwd)        */
#define NWAVE  4                 /* strips per WG per direction            */
#define STRIPROWS 128            /* rows per strip (2 per lane)            */
#define KSTEP  16                /* steps per superstep (barrier cadence)  */
#define CPFD   4                 /* LDS->reg cost prefetch depth (steps)   */
#define EXTD   4                 /* LDS-ring prefetch distance (steps)     */
#define TSTEPS 4752              /* >= 4094 + Og(15)=648 + 1; 297*16       */
#define NSUPER (TSTEPS / KSTEP)
#define GRING  1024              /* global ring entries per WG boundary    */
#define LRING  256               /* LDS ring entries per strip boundary    */
// Strip g skew: Og = 24g + 96*(g/4)  (intra-WG lag 24 >= KSTEP+EXTD+1=21;
// inter-WG DS = 248 >= 207 from the flag-slack inequality; ≡0 mod 8 so
// prefetch slots stay static). S_use(g) = Og + 128g = 152g + 96*(g/4).

constexpr float K2      = 14.426950408889634f;   // log2(e)/gamma, gamma=0.1
constexpr float INF_K   = 1.0e10f * 14.426950408889634f;
constexpr float UNSCALE = 0.06931471805599453f;  // gamma*ln2 = 1/K2

// Packed anti-diagonal layout for a 2048x2048 matrix: diag d = i+j, 0..4094.
__device__ __forceinline__ int diag_off(int d) {
    return (d < NN) ? ((d * (d + 1)) >> 1)
                    : (TOTCELLS - (((NDIAG - d) * (NDIAG - d + 1)) >> 1));
}
__device__ __forceinline__ int diag_imin(int d) { return (d < NN) ? 0 : (d - (NN - 1)); }
__device__ __forceinline__ int diag_len(int d)  { return (d < NN) ? (d + 1) : (NDIAG - d); }

__device__ __forceinline__ float fexp2(float x) { return __builtin_amdgcn_exp2f(x); }
__device__ __forceinline__ float flog2(float x) { return __builtin_amdgcn_logf(x); }

// rotate-up-by-1 across the wave via DPP wave_ror:1 (0x13C): lane l gets
// lane (l-1)&63's value at VALU latency. Lane 0's result is overridden.
__device__ __forceinline__ float rot_up1(float x) {
    int xi = __builtin_bit_cast(int, x);
    int r  = __builtin_amdgcn_update_dpp(xi, xi, 0x13C, 0xF, 0xF, true);
    return __builtin_bit_cast(float, r);
}

// softmin in the K2-scaled (log2) domain: m1 - log2(1 + 2^(m1-m2) + 2^(m1-m3))
__device__ __forceinline__ float softmin3k(float a, float b, float c) {
    const float m1 = fminf(fminf(a, b), c);
    const float m2 = __builtin_amdgcn_fmed3f(a, b, c);
    const float m3 = fmaxf(fmaxf(a, b), c);
    const float e  = 1.0f + fexp2(m1 - m2) + fexp2(m1 - m3);
    return m1 - flog2(e);
}

// ---------------------------------------------------------------------------
// cost[i,j] = K2 * sum_k (target[i,k]-pred[j,k])^2, packed diag layout.
// Block (0,0) also zeroes accumulators + pipeline flags (80 words).
// ---------------------------------------------------------------------------
__global__ __launch_bounds__(256) void cost_kernel(const float* __restrict__ pred,
                                                   const float* __restrict__ target,
                                                   float* __restrict__ costD,
                                                   float* __restrict__ acc) {
    __shared__ float Ts[64][65];
    __shared__ float Ps[64][65];
    const int tid = threadIdx.x;
    const int tx = tid & 15, ty = tid >> 4;
    const int i0 = blockIdx.y * 64;
    const int j0 = blockIdx.x * 64;

    if (blockIdx.x == 0 && blockIdx.y == 0 && tid < 80) ((unsigned*)acc)[tid] = 0u;

    #pragma unroll
    for (int rnd = 0; rnd < 4; ++rnd) {
        int f4i = tid + rnd * 256;
        int r  = f4i >> 4;
        int k4 = (f4i & 15) << 2;
        float4 tv = *reinterpret_cast<const float4*>(target + (size_t)(i0 + r) * DD + k4);
        Ts[r][k4 + 0] = tv.x; Ts[r][k4 + 1] = tv.y; Ts[r][k4 + 2] = tv.z; Ts[r][k4 + 3] = tv.w;
        float4 pv = *reinterpret_cast<const float4*>(pred + (size_t)(j0 + r) * DD + k4);
        Ps[k4 + 0][r] = pv.x; Ps[k4 + 1][r] = pv.y; Ps[k4 + 2][r] = pv.z; Ps[k4 + 3][r] = pv.w;
    }
    __syncthreads();

    float accv[4][4];
    #pragma unroll
    for (int a = 0; a < 4; ++a)
        #pragma unroll
        for (int b = 0; b < 4; ++b) accv[a][b] = 0.f;

    for (int k = 0; k < 64; ++k) {
        float ta[4], pb[4];
        #pragma unroll
        for (int a = 0; a < 4; ++a) ta[a] = Ts[ty + 16 * a][k];
        #pragma unroll
        for (int b = 0; b < 4; ++b) pb[b] = Ps[k][tx + 16 * b];
        #pragma unroll
        for (int a = 0; a < 4; ++a)
            #pragma unroll
            for (int b = 0; b < 4; ++b) {
                float d = ta[a] - pb[b];
                accv[a][b] = fmaf(d, d, accv[a][b]);
            }
    }
    #pragma unroll
    for (int a = 0; a < 4; ++a) {
        int i = i0 + ty + 16 * a;
        #pragma unroll
        for (int b = 0; b < 4; ++b) {
            int j = j0 + tx + 16 * b;
            int d = i + j;
            costD[diag_off(d) + (i - diag_imin(d))] = accv[a][b] * K2;
        }
    }
}

// ---------------------------------------------------------------------------
// Skewed register-resident soft-DTW, cost staged through LDS, with fwd and
// bwd sweeps co-resident in the SAME workgroup (waves 0-3 fwd, 4-7 bwd) so
// each SIMD hosts 2 waves and latency-class stalls (TRANS, DS, store issue,
// staging drain) of one wave are covered by the other. bwd runs as forward
// on the 180-rotated cost (identity flat_orig = TOTCELLS-1-flat_rot, handled
// in staging source addresses only; LDS stays rot-linear). The step loop
// performs ZERO global loads: cost arrives via global_load_lds staging
// (issued one superstep ahead, drained once at the barrier) and is consumed
// through a 4-deep ds_read register ring on lgkmcnt.
// ---------------------------------------------------------------------------
__global__ __launch_bounds__(512) void dp_pipe(const float* __restrict__ costD,
                                               float* __restrict__ fwdD,
                                               float* __restrict__ bwdD,
                                               unsigned* __restrict__ flagsP,
                                               float* __restrict__ gringP) {
    __shared__ float cls[2][2 * NWAVE][KSTEP][STRIPROWS];   // 128 KB cost staging
    __shared__ float ringAll[2 * (NWAVE + 1)][LRING];       // 10 KB boundary rings
    const int wg   = (int)blockIdx.x;
    const int tid  = threadIdx.x;
    const int wv   = tid >> 6;        // 0..7
    const int dirw = wv >> 2;         // 0 = fwd, 1 = bwd
    const int sv   = wv & 3;          // strip-in-WG (per direction)
    const int lane = tid & 63;
    const int g    = wg * NWAVE + sv; // strip id 0..15 in this direction
    const int gu   = __builtin_amdgcn_readfirstlane(g);
    const int Og   = __builtin_amdgcn_readfirstlane(24 * g + 96 * (g >> 2));
    const int Suse = __builtin_amdgcn_readfirstlane(152 * g + 96 * (g >> 2));
    const int r0   = STRIPROWS * g + 2 * lane;
    float* __restrict__ outD = dirw ? bwdD : fwdD;
    unsigned* pf = flagsP + dirw * NWGD;
    float* grd   = gringP + (size_t)dirw * 3 * GRING;
    const float* mring = ringAll[dirw * (NWAVE + 1) + ((sv == 0) ? NWAVE : (sv - 1))];
    float* pring = ringAll[dirw * (NWAVE + 1) + sv];
    float* xring = ringAll[dirw * (NWAVE + 1) + NWAVE];
    const int sgn = dirw ? -1 : 1;

    // incremental per-lane output address: aS tracks diag dd
    int aS;
    {
        const int b0 = r0;                        // flat_rot at dd=0
        aS = dirw ? (TOTCELLS - 1 - b0) : b0;
    }

    // Stage KSTEP slices (diags tb-Og .. tb-Og+15, rows 128g..128g+127) into
    // cls[bsel][wv]. LDS dest is wave-uniform base + lane*4 (linear, rot
    // order); the dir-1 reversal lives in the per-lane GLOBAL src address.
    auto STAGE = [&](int tb, int bsel) {
        #pragma unroll 8
        for (int j = 0; j < 32; ++j) {
            const int s  = j >> 1;
            const int e0 = (j & 1) << 6;          // 0 or 64
            const int dd = tb + s - Og;           // may be out of range
            const int ddc = (dd < 0) ? 0 : ((dd > NDIAG - 1) ? NDIAG - 1 : dd);
            const int rb  = diag_off(ddc) - diag_imin(ddc) + STRIPROWS * gu;
            int src = rb + e0 + lane;             // rot-flat of rot row e
            if (dirw) src = (TOTCELLS - 1) - src; // packed-layout rotation
            src = (src < 0) ? 0 : ((src > TOTCELLS - 1) ? (TOTCELLS - 1) : src);
            __builtin_amdgcn_global_load_lds(
                (const __attribute__((address_space(1))) void*)(costD + src),
                (__attribute__((address_space(3))) void*)&cls[bsel][wv][s][e0],
                4, 0, 0);
        }
    };

    float Rk0 = INF_K, Rk0m1 = INF_K, Rk1 = INF_K;
    float dg0 = (g == 0 && lane == 0) ? 0.0f : INF_K;  // virtual R[0,0]=0
    float ext[8];
    #pragma unroll
    for (int z = 0; z < 8; ++z) ext[z] = INF_K;

    // prologue: stage buffer 0 (diags -Og .. -Og+15), then make it visible
    STAGE(0, 0);
    __syncthreads();

    for (unsigned m = 0; m < NSUPER; ++m) {
        const int tbase = (int)(m * KSTEP);
        const int bsel  = (int)(m & 1);

        // ---- inter-WG gather (sv0, wg>0): columns [c0g, c0g+63] -> xring
        if (sv == 0 && wg > 0) {
            const int c0g = tbase - Suse;
            if (c0g + 63 >= 0 && c0g < NN) {
                const unsigned need = m - 1;
                unsigned guard = 0;
                while (__hip_atomic_load(&pf[wg - 1], __ATOMIC_ACQUIRE,
                                         __HIP_MEMORY_SCOPE_AGENT) < need &&
                       guard < (1u << 20)) { __builtin_amdgcn_s_sleep(8); ++guard; }
                const int c = c0g + lane;
                if (c >= 0 && c < NN)
                    xring[c & (LRING - 1)] =
                        __hip_atomic_load(&grd[(wg - 1) * GRING + (c & (GRING - 1))],
                                          __ATOMIC_RELAXED, __HIP_MEMORY_SCOPE_AGENT);
            }
        }

        // ---- issue staging for the NEXT superstep (drained at the barrier)
        if (m + 1 < NSUPER) STAGE(tbase + KSTEP, bsel ^ 1);

        // ---- LDS->reg cost prologue: slots for q = 0..3
        float2 ccr[CPFD];
        #pragma unroll
        for (int p = 0; p < CPFD; ++p)
            ccr[p] = *reinterpret_cast<const float2*>(&cls[bsel][wv][p][2 * lane]);

        // ---- 16 wavefront steps (two 8-unrolled groups; slots static)
        for (int tu = 0; tu < KSTEP; tu += 8) {
            #pragma unroll
            for (int q8 = 0; q8 < 8; ++q8) {
                const int q  = tu + q8;
                const int t  = tbase + q;
                const int dd = t - Og;             // wave-uniform
                // consume cost slot (ds_read issued CPFD steps ago), then refill
                const float uc0 = ccr[q8 & 3].x;
                const float uc1 = ccr[q8 & 3].y;
                if (q < KSTEP - CPFD)
                    ccr[q8 & 3] = *reinterpret_cast<const float2*>(
                        &cls[bsel][wv][q + CPFD][2 * lane]);
                if (dd >= 0 && dd < NDIAG) {
                    const int ec = t - Suse;       // boundary column this step
                    float extv = INF_K;
                    if (g != 0 && ec >= 0 && ec < NN) extv = ext[q8];
                    if (g != 0)                    // prefetch ring value for t+EXTD
                        ext[(q8 + EXTD) & 7] =
                            mring[((unsigned)(t + EXTD - Suse)) & (LRING - 1)];
                    const float shr = rot_up1(Rk1);          // neighbor row r0-1
                    const float up0 = (lane == 0) ? extv : shr;
                    const float n0 = uc0 + softmin3k(dg0, up0, Rk0);
                    const float n1 = uc1 + softmin3k(Rk0m1, Rk0, Rk1);
                    const int c0 = dd - r0;
                    const bool v0 = (c0 >= 0) && (c0 < NN);
                    const bool v1 = (c0 >= 1) && (c0 <= NN);
                    Rk0m1 = Rk0;
                    if (v0) Rk0 = n0;
                    if (v1) Rk1 = n1;
                    dg0 = up0;
                    if (v0) outD[aS] = Rk0;
                    if (v1) outD[aS + sgn] = Rk1;
                    const int pc = ec - (STRIPROWS - 1);   // publish last row
                    if (lane == 63 && pc >= 0 && pc < NN)
                        pring[pc & (LRING - 1)] = Rk1;
                    const int ds = (dd + 1 < NDIAG - 1 - dd) ? (dd + 1) : (NDIAG - 1 - dd);
                    aS += sgn * ds;
                }
            }
        }
        __syncthreads();

        // ---- inter-WG flush (sv0): ring[strip3] -> global ring, then flag
        if (sv == 0 && wg < NWGD - 1) {
            const int Sp = 704 * wg + 456;          // S_use of strip 4wg+3
            const int cb = tbase - Sp - (STRIPROWS - 1);
            if (lane < KSTEP) {
                const int c = cb + lane;
                if (c >= 0 && c < NN)
                    __hip_atomic_store(&grd[wg * GRING + (c & (GRING - 1))],
                                       ringAll[dirw * (NWAVE + 1) + NWAVE - 1][c & (LRING - 1)],
                                       __ATOMIC_RELAXED, __HIP_MEMORY_SCOPE_AGENT);
            }
            if (lane == 0)
                __hip_atomic_store(&pf[wg], m + 1, __ATOMIC_RELEASE,
                                   __HIP_MEMORY_SCOPE_AGENT);
        }
    }
}

// ---------------------------------------------------------------------------
// Per-cell alignment + linear reductions. a = exp2(-max(f + B - dist, 0)).
// acc: [0]=total [1]=temporal [2]=boundary [3..17]=seg mass [18..32]=seg pos
// ---------------------------------------------------------------------------
__device__ __forceinline__ float wave_red(float v) {
    v += __shfl_xor(v, 32, 64);
    v += __shfl_xor(v, 16, 64);
    v += __shfl_xor(v, 8, 64);
    v += __shfl_xor(v, 4, 64);
    v += __shfl_xor(v, 2, 64);
    v += __shfl_xor(v, 1, 64);
    return v;
}

__global__ __launch_bounds__(256) void combine_kernel(const float* __restrict__ fwdD,
                                                      const float* __restrict__ bwdD,
                                                      const int* __restrict__ gbp, int ngb,
                                                      float* __restrict__ acc) {
    const int d = blockIdx.x;
    const int ofs = diag_off(d), imin = diag_imin(d), len = diag_len(d);
    const float dist = fwdD[TOTCELLS - 1];
    __shared__ float sseg[MAXSEG], ssegp[MAXSEG];
    __shared__ int sgb[MAXSEG + 1];
    const int tid = threadIdx.x;
    if (tid < MAXSEG) { sseg[tid] = 0.f; ssegp[tid] = 0.f; }
    if (tid < ngb && tid <= MAXSEG) sgb[tid] = gbp[tid];
    __syncthreads();

    float pT = 0.f, pTe = 0.f, pB = 0.f;
    const float invM1 = 1.f / (float)(MM - 1);
    const float invN1 = 1.f / (float)(NN - 1);
    const int nseg = ngb - 1;

    for (int x = tid; x < len; x += 256) {
        const int i0 = imin + x, j0 = d - i0;
        const float f = fwdD[ofs + x], b = bwdD[ofs + x];
        const float a = fexp2(-fmaxf(f + b - dist, 0.0f));
        const float jp = j0 * invN1, ip = i0 * invM1;
        pT += a;
        const float dt = ip - jp;
        pTe += a * dt * dt;
        int s = -1;
        for (int q = 0; q < nseg && q < MAXSEG; ++q)
            if (i0 >= sgb[q] && i0 < sgb[q + 1]) s = q;
        if (s >= 0) { atomicAdd(&sseg[s], a); atomicAdd(&ssegp[s], a * jp); }
        for (int q = 0; q < ngb && q <= MAXSEG; ++q) {
            const int bv = sgb[q];
            if (bv > 0 && bv < MM && i0 == bv) {
                const float dv = jp - (float)bv * invM1;
                pB += a * dv * dv;
            }
        }
    }
    pT = wave_red(pT); pTe = wave_red(pTe); pB = wave_red(pB);
    if ((tid & 63) == 0) {
        if (pT  != 0.f) atomicAdd(&acc[0], pT);
        if (pTe != 0.f) atomicAdd(&acc[1], pTe);
        if (pB  != 0.f) atomicAdd(&acc[2], pB);
    }
    __syncthreads();
    if (tid < nseg && tid < MAXSEG) {
        if (sseg[tid]  != 0.f) atomicAdd(&acc[3 + tid], sseg[tid]);
        if (ssegp[tid] != 0.f) atomicAdd(&acc[3 + MAXSEG + tid], ssegp[tid]);
    }
}

// ---------------------------------------------------------------------------
// Scalar epilogue replicating the reference's scale/order/coverage semantics.
// ---------------------------------------------------------------------------
__global__ void final_kernel(const float* __restrict__ acc,
                             const float* __restrict__ fwdD,
                             const int* __restrict__ gbp, int ngb,
                             float* __restrict__ out) {
    if (threadIdx.x != 0 || blockIdx.x != 0) return;
    const float dist = fwdD[TOTCELLS - 1] * UNSCALE;   // unscale shape loss
    const float Utot = acc[0];
    const float scale = (Utot > 1e-8f) ? ((float)(MM < NN ? MM : NN) / fmaxf(Utot, 1e-8f)) : 1.0f;
    const float temporal = scale * acc[1];

    int gb[MAXSEG + 1];
    const int n = (ngb <= MAXSEG + 1) ? ngb : (MAXSEG + 1);
    for (int q = 0; q < n; ++q) gb[q] = gbp[q];

    int nint = 0;
    for (int q = 0; q < n; ++q) if (gb[q] > 0 && gb[q] < MM) nint++;
    const float boundary = (nint > 0) ? (scale * acc[2] / (float)nint) : 0.f;

    float order = 0.f;
    if (n > 2) {
        float pos[MAXSEG];
        int np = 0;
        for (int s = 0; s + 1 < n; ++s) {
            const int st = gb[s], en = gb[s + 1];
            if (st >= MM || en > MM || st >= en) continue;
            const float mass = fmaxf(scale * acc[3 + s], 1e-8f);
            pos[np++] = scale * acc[3 + MAXSEG + s] / mass;
        }
        for (int k = 1; k < np; ++k) order += fmaxf(pos[k - 1] - pos[k], 0.f);
        if (np > 1) order /= (float)(np - 1);
    }

    float cov = 0.f;
    const int nsteps = n - 1;
    if (nsteps > 0) {
        for (int s = 0; s < nsteps; ++s) {
            const int st = gb[s];
            int en = gb[s + 1]; if (en > MM) en = MM;
            if (st >= en) continue;
            cov += fmaxf((float)(en - st) * 0.5f - scale * acc[3 + s], 0.f);
        }
        cov /= (float)nsteps;
    }

    out[0] = 0.3f * dist + 0.2f * temporal + 0.2f * boundary + 0.15f * order + 0.15f * cov;
}

// ---------------------------------------------------------------------------
extern "C" void kernel_launch(void* const* d_in, const int* in_sizes, int n_in,
                              void* d_out, int out_size, void* d_ws, size_t ws_size,
                              hipStream_t stream) {
    const float* pred   = (const float*)d_in[0];   // (2048, 64)
    const float* target = (const float*)d_in[1];   // (2048, 64)
    const int*   gb     = (const int*)d_in[2];     // (9,)
    const int ngb = in_sizes[2];

    float* costD = (float*)d_ws;
    float* fwdD  = costD + TOTCELLS;
    float* bwdD  = fwdD + TOTCELLS;
    float* acc   = bwdD + TOTCELLS;                 // 64 floats (zeroed by cost_kernel)
    unsigned* flagsP = (unsigned*)(acc + 64);       // [2][4] producer progress (zeroed)
    float* gringP    = (float*)(flagsP + 2 * NWGD); // [2][3][GRING]

    cost_kernel<<<dim3(NN / 64, MM / 64), 256, 0, stream>>>(pred, target, costD, acc);
    dp_pipe<<<NWGD, 2 * NWAVE * 64, 0, stream>>>(costD, fwdD, bwdD, flagsP, gringP);
    combine_kernel<<<NDIAG, 256, 0, stream>>>(fwdD, bwdD, gb, ngb, acc);
    final_kernel<<<1, 64, 0, stream>>>(acc, fwdD, gb, ngb, (float*)d_out);
}

// Round 9
// 1811.547 us; speedup vs baseline: 1.2438x; 1.2438x over previous
//
#include <hip/hip_runtime.h>

#define MM 2048
#define NN 2048
#define DD 64
#define NDIAG (MM + NN - 1)      /* 4095 cost-matrix anti-diagonals */
#define TOTCELLS (MM * NN)
#define MAXSEG 15

// ---- skewed-pipeline DP geometry (R6 layout: 8 WGs, dirs separate) ----
#define NWGD   4                 /* workgroups per direction               */
#define NWAVE  4                 /* waves per WG (1 strip per wave)        */
#define STRIPROWS 128            /* rows per strip (2 per lane)            */
#define KSTEP  32                /* steps per superstep (barrier cadence)  */
#define HSTEP  16                /* half-superstep: batch granularity      */
#define TSTEPS 4992              /* >= 4094 + Og(15)=888 + 1; 156*32       */
#define NSUPER (TSTEPS / KSTEP)
#define GRING  1024              /* global ring entries per WG boundary    */
#define LRING  256               /* LDS ring entries per strip boundary    */
// Strip g skew: Og = 40g + 96*(g/4); S_use(g) = Og + 128g = 168g + 96*(g/4).
// Intra-WG lag 41: ring value for column ec (consumed at wall t = ec+Suse,
// batched at most 31 steps earlier) is written at wall t-41 <= t_base-10,
// i.e. before the superstep barrier -> batch reads are race-free.

constexpr float K2      = 14.426950408889634f;   // log2(e)/gamma, gamma=0.1
constexpr float INF_K   = 1.0e10f * 14.426950408889634f;
constexpr float UNSCALE = 0.06931471805599453f;  // gamma*ln2 = 1/K2

// Packed anti-diagonal layout for a 2048x2048 matrix: diag d = i+j, 0..4094.
__device__ __forceinline__ int diag_off(int d) {
    return (d < NN) ? ((d * (d + 1)) >> 1)
                    : (TOTCELLS - (((NDIAG - d) * (NDIAG - d + 1)) >> 1));
}
__device__ __forceinline__ int diag_imin(int d) { return (d < NN) ? 0 : (d - (NN - 1)); }
__device__ __forceinline__ int diag_len(int d)  { return (d < NN) ? (d + 1) : (NDIAG - d); }

__device__ __forceinline__ float fexp2(float x) { return __builtin_amdgcn_exp2f(x); }
__device__ __forceinline__ float flog2(float x) { return __builtin_amdgcn_logf(x); }

// rotate-up-by-1 across the wave via DPP wave_ror:1 (0x13C): lane l gets
// lane (l-1)&63's value at VALU latency. Lane 0's result is overridden.
__device__ __forceinline__ float rot_up1(float x) {
    int xi = __builtin_bit_cast(int, x);
    int r  = __builtin_amdgcn_update_dpp(xi, xi, 0x13C, 0xF, 0xF, true);
    return __builtin_bit_cast(float, r);
}

// softmin in the K2-scaled (log2) domain: m1 - log2(1 + 2^(m1-m2) + 2^(m1-m3))
__device__ __forceinline__ float softmin3k(float a, float b, float c) {
    const float m1 = fminf(fminf(a, b), c);
    const float m2 = __builtin_amdgcn_fmed3f(a, b, c);
    const float m3 = fmaxf(fmaxf(a, b), c);
    const float e  = 1.0f + fexp2(m1 - m2) + fexp2(m1 - m3);
    return m1 - flog2(e);
}

// ---------------------------------------------------------------------------
// cost[i,j] = K2 * sum_k (target[i,k]-pred[j,k])^2, packed diag layout.
// Block (0,0) also zeroes accumulators + pipeline flags (80 words).
// ---------------------------------------------------------------------------
__global__ __launch_bounds__(256) void cost_kernel(const float* __restrict__ pred,
                                                   const float* __restrict__ target,
                                                   float* __restrict__ costD,
                                                   float* __restrict__ acc) {
    __shared__ float Ts[64][65];
    __shared__ float Ps[64][65];
    const int tid = threadIdx.x;
    const int tx = tid & 15, ty = tid >> 4;
    const int i0 = blockIdx.y * 64;
    const int j0 = blockIdx.x * 64;

    if (blockIdx.x == 0 && blockIdx.y == 0 && tid < 80) ((unsigned*)acc)[tid] = 0u;

    #pragma unroll
    for (int rnd = 0; rnd < 4; ++rnd) {
        int f4i = tid + rnd * 256;
        int r  = f4i >> 4;
        int k4 = (f4i & 15) << 2;
        float4 tv = *reinterpret_cast<const float4*>(target + (size_t)(i0 + r) * DD + k4);
        Ts[r][k4 + 0] = tv.x; Ts[r][k4 + 1] = tv.y; Ts[r][k4 + 2] = tv.z; Ts[r][k4 + 3] = tv.w;
        float4 pv = *reinterpret_cast<const float4*>(pred + (size_t)(j0 + r) * DD + k4);
        Ps[k4 + 0][r] = pv.x; Ps[k4 + 1][r] = pv.y; Ps[k4 + 2][r] = pv.z; Ps[k4 + 3][r] = pv.w;
    }
    __syncthreads();

    float accv[4][4];
    #pragma unroll
    for (int a = 0; a < 4; ++a)
        #pragma unroll
        for (int b = 0; b < 4; ++b) accv[a][b] = 0.f;

    for (int k = 0; k < 64; ++k) {
        float ta[4], pb[4];
        #pragma unroll
        for (int a = 0; a < 4; ++a) ta[a] = Ts[ty + 16 * a][k];
        #pragma unroll
        for (int b = 0; b < 4; ++b) pb[b] = Ps[k][tx + 16 * b];
        #pragma unroll
        for (int a = 0; a < 4; ++a)
            #pragma unroll
            for (int b = 0; b < 4; ++b) {
                float d = ta[a] - pb[b];
                accv[a][b] = fmaf(d, d, accv[a][b]);
            }
    }
    #pragma unroll
    for (int a = 0; a < 4; ++a) {
        int i = i0 + ty + 16 * a;
        #pragma unroll
        for (int b = 0; b < 4; ++b) {
            int j = j0 + tx + 16 * b;
            int d = i + j;
            costD[diag_off(d) + (i - diag_imin(d))] = accv[a][b] * K2;
        }
    }
}

// ---------------------------------------------------------------------------
// Skewed register-resident soft-DTW (R6 structure) with BATCHED LDS->reg
// traffic: per half-superstep, 16x ds_read_b64 (cost) + 16 ring reads land
// in registers in one pipelined lgkmcnt region; the 16 fully-unrolled steps
// that follow are pure-register (DPP rotate + 2 softmin + 2 stores) with no
// LDS or global loads, eliminating per-step lgkmcnt waits. blocks 0-3: fwd;
// blocks 4-7: bwd as forward on the 180-rotated cost (flat_orig =
// TOTCELLS-1-flat_rot, handled in staging source addresses only).
// ---------------------------------------------------------------------------
__global__ __launch_bounds__(256) void dp_pipe(const float* __restrict__ costD,
                                               float* __restrict__ fwdD,
                                               float* __restrict__ bwdD,
                                               unsigned* __restrict__ flagsP,
                                               float* __restrict__ gringP) {
    __shared__ float cls[2][NWAVE][KSTEP][STRIPROWS];   // 128 KB cost staging
    __shared__ float ring[NWAVE + 1][LRING];            // 5 KB boundary rings
    const int dir  = (int)blockIdx.x >> 2;
    const int wg   = (int)blockIdx.x & 3;
    const int tid  = threadIdx.x;
    const int wv   = tid >> 6;
    const int lane = tid & 63;
    const int g    = wg * NWAVE + wv;
    const int gu   = __builtin_amdgcn_readfirstlane(g);
    const int Og   = __builtin_amdgcn_readfirstlane(40 * g + 96 * (g >> 2));
    const int Suse = __builtin_amdgcn_readfirstlane(152 * g + 96 * (g >> 2) + 16 * g);
    const int r0   = STRIPROWS * g + 2 * lane;
    float* __restrict__ outD = dir ? bwdD : fwdD;
    unsigned* pf = flagsP + dir * NWGD;
    float* grd   = gringP + (size_t)dir * 3 * GRING;
    const float* mring = ring[(wv == 0) ? NWAVE : (wv - 1)];
    const int sgn = dir ? -1 : 1;

    // incremental per-lane output address: aS tracks diag dd
    int aS;
    {
        const int b0 = r0;                        // flat_rot at dd=0
        aS = dir ? (TOTCELLS - 1 - b0) : b0;
    }

    // Stage KSTEP slices (diags tb-Og .. tb-Og+31, rows 128g..128g+127) into
    // cls[bsel][wv]. LDS dest is wave-uniform base + lane*4 (linear, rot
    // order); the dir-1 reversal lives in the per-lane GLOBAL src address.
    auto STAGE = [&](int tb, int bsel) {
        #pragma unroll 8
        for (int j = 0; j < 64; ++j) {
            const int s  = j >> 1;
            const int e0 = (j & 1) << 6;          // 0 or 64
            const int dd = tb + s - Og;           // may be out of range
            const int ddc = (dd < 0) ? 0 : ((dd > NDIAG - 1) ? NDIAG - 1 : dd);
            const int rb  = diag_off(ddc) - diag_imin(ddc) + STRIPROWS * gu;
            int src = rb + e0 + lane;             // rot-flat of rot row e
            if (dir) src = (TOTCELLS - 1) - src;  // packed-layout rotation
            src = (src < 0) ? 0 : ((src > TOTCELLS - 1) ? (TOTCELLS - 1) : src);
            __builtin_amdgcn_global_load_lds(
                (const __attribute__((address_space(1))) void*)(costD + src),
                (__attribute__((address_space(3))) void*)&cls[bsel][wv][s][e0],
                4, 0, 0);
        }
    };

    float Rk0 = INF_K, Rk0m1 = INF_K, Rk1 = INF_K;
    float dg0 = (g == 0 && lane == 0) ? 0.0f : INF_K;  // virtual R[0,0]=0

    // prologue: stage buffer 0 (diags -Og .. -Og+31), then make it visible
    STAGE(0, 0);
    __syncthreads();

    for (unsigned m = 0; m < NSUPER; ++m) {
        const int tbase = (int)(m * KSTEP);
        const int bsel  = (int)(m & 1);

        // ---- inter-WG gather (wv0, wg>0): columns [c0g, c0g+63] -> ring[4]
        if (wv == 0 && wg > 0) {
            const int c0g = tbase - Suse;
            if (c0g + 63 >= 0 && c0g < NN) {
                const unsigned need = m - 1;
                unsigned guard = 0;
                while (__hip_atomic_load(&pf[wg - 1], __ATOMIC_ACQUIRE,
                                         __HIP_MEMORY_SCOPE_AGENT) < need &&
                       guard < (1u << 20)) { __builtin_amdgcn_s_sleep(8); ++guard; }
                const int c = c0g + lane;
                if (c >= 0 && c < NN)
                    ring[NWAVE][c & (LRING - 1)] =
                        __hip_atomic_load(&grd[(wg - 1) * GRING + (c & (GRING - 1))],
                                          __ATOMIC_RELAXED, __HIP_MEMORY_SCOPE_AGENT);
            }
        }

        // ---- issue staging for the NEXT superstep (drained at the barrier)
        if (m + 1 < NSUPER) STAGE(tbase + KSTEP, bsel ^ 1);

        // ---- two half-supersteps: batch LDS->reg, then 16 pure-reg steps
        #pragma unroll
        for (int h = 0; h < 2; ++h) {
            const int tb16 = tbase + h * HSTEP;
            float2 ccb[HSTEP];
            float  extb[HSTEP];
            #pragma unroll
            for (int p = 0; p < HSTEP; ++p)
                ccb[p] = *reinterpret_cast<const float2*>(
                    &cls[bsel][wv][h * HSTEP + p][2 * lane]);
            if (g != 0) {
                #pragma unroll
                for (int p = 0; p < HSTEP; ++p)
                    extb[p] = mring[((unsigned)(tb16 + p - Suse)) & (LRING - 1)];
            } else {
                #pragma unroll
                for (int p = 0; p < HSTEP; ++p) extb[p] = INF_K;
            }

            #pragma unroll
            for (int p = 0; p < HSTEP; ++p) {
                const int t  = tb16 + p;
                const int dd = t - Og;             // wave-uniform (SALU guard)
                if (dd >= 0 && dd < NDIAG) {
                    const int ec = t - Suse;       // boundary column this step
                    float extv = INF_K;
                    if (g != 0 && ec >= 0 && ec < NN) extv = extb[p];
                    const float shr = rot_up1(Rk1);          // neighbor row r0-1
                    const float up0 = (lane == 0) ? extv : shr;
                    const float n0 = ccb[p].x + softmin3k(dg0, up0, Rk0);
                    const float n1 = ccb[p].y + softmin3k(Rk0m1, Rk0, Rk1);
                    const int c0 = dd - r0;
                    const bool v0 = (c0 >= 0) && (c0 < NN);
                    const bool v1 = (c0 >= 1) && (c0 <= NN);
                    Rk0m1 = Rk0;
                    if (v0) Rk0 = n0;
                    if (v1) Rk1 = n1;
                    dg0 = up0;
                    if (v0) outD[aS] = Rk0;
                    if (v1) outD[aS + sgn] = Rk1;
                    const int pc = ec - (STRIPROWS - 1);   // publish last row
                    if (lane == 63 && pc >= 0 && pc < NN)
                        ring[wv][pc & (LRING - 1)] = Rk1;
                    const int ds = (dd + 1 < NDIAG - 1 - dd) ? (dd + 1) : (NDIAG - 1 - dd);
                    aS += sgn * ds;
                }
            }
        }
        __syncthreads();

        // ---- inter-WG flush (wv0): ring[3] -> global ring, then flag
        if (wv == 0 && wg < NWGD - 1) {
            const int Sp = 768 * wg + 504;          // S_use of strip 4wg+3
            const int cb = tbase - Sp - (STRIPROWS - 1);
            if (lane < KSTEP) {
                const int c = cb + lane;
                if (c >= 0 && c < NN)
                    __hip_atomic_store(&grd[wg * GRING + (c & (GRING - 1))],
                                       ring[NWAVE - 1][c & (LRING - 1)],
                                       __ATOMIC_RELAXED, __HIP_MEMORY_SCOPE_AGENT);
            }
            if (lane == 0)
                __hip_atomic_store(&pf[wg], m + 1, __ATOMIC_RELEASE,
                                   __HIP_MEMORY_SCOPE_AGENT);
        }
    }
}

// ---------------------------------------------------------------------------
// Per-cell alignment + linear reductions. a = exp2(-max(f + B - dist, 0)).
// acc: [0]=total [1]=temporal [2]=boundary [3..17]=seg mass [18..32]=seg pos
// ---------------------------------------------------------------------------
__device__ __forceinline__ float wave_red(float v) {
    v += __shfl_xor(v, 32, 64);
    v += __shfl_xor(v, 16, 64);
    v += __shfl_xor(v, 8, 64);
    v += __shfl_xor(v, 4, 64);
    v += __shfl_xor(v, 2, 64);
    v += __shfl_xor(v, 1, 64);
    return v;
}

__global__ __launch_bounds__(256) void combine_kernel(const float* __restrict__ fwdD,
                                                      const float* __restrict__ bwdD,
                                                      const int* __restrict__ gbp, int ngb,
                                                      float* __restrict__ acc) {
    const int d = blockIdx.x;
    const int ofs = diag_off(d), imin = diag_imin(d), len = diag_len(d);
    const float dist = fwdD[TOTCELLS - 1];
    __shared__ float sseg[MAXSEG], ssegp[MAXSEG];
    __shared__ int sgb[MAXSEG + 1];
    const int tid = threadIdx.x;
    if (tid < MAXSEG) { sseg[tid] = 0.f; ssegp[tid] = 0.f; }
    if (tid < ngb && tid <= MAXSEG) sgb[tid] = gbp[tid];
    __syncthreads();

    float pT = 0.f, pTe = 0.f, pB = 0.f;
    const float invM1 = 1.f / (float)(MM - 1);
    const float invN1 = 1.f / (float)(NN - 1);
    const int nseg = ngb - 1;

    for (int x = tid; x < len; x += 256) {
        const int i0 = imin + x, j0 = d - i0;
        const float f = fwdD[ofs + x], b = bwdD[ofs + x];
        const float a = fexp2(-fmaxf(f + b - dist, 0.0f));
        const float jp = j0 * invN1, ip = i0 * invM1;
        pT += a;
        const float dt = ip - jp;
        pTe += a * dt * dt;
        int s = -1;
        for (int q = 0; q < nseg && q < MAXSEG; ++q)
            if (i0 >= sgb[q] && i0 < sgb[q + 1]) s = q;
        if (s >= 0) { atomicAdd(&sseg[s], a); atomicAdd(&ssegp[s], a * jp); }
        for (int q = 0; q < ngb && q <= MAXSEG; ++q) {
            const int bv = sgb[q];
            if (bv > 0 && bv < MM && i0 == bv) {
                const float dv = jp - (float)bv * invM1;
                pB += a * dv * dv;
            }
        }
    }
    pT = wave_red(pT); pTe = wave_red(pTe); pB = wave_red(pB);
    if ((tid & 63) == 0) {
        if (pT  != 0.f) atomicAdd(&acc[0], pT);
        if (pTe != 0.f) atomicAdd(&acc[1], pTe);
        if (pB  != 0.f) atomicAdd(&acc[2], pB);
    }
    __syncthreads();
    if (tid < nseg && tid < MAXSEG) {
        if (sseg[tid]  != 0.f) atomicAdd(&acc[3 + tid], sseg[tid]);
        if (ssegp[tid] != 0.f) atomicAdd(&acc[3 + MAXSEG + tid], ssegp[tid]);
    }
}

// ---------------------------------------------------------------------------
// Scalar epilogue replicating the reference's scale/order/coverage semantics.
// ---------------------------------------------------------------------------
__global__ void final_kernel(const float* __restrict__ acc,
                             const float* __restrict__ fwdD,
                             const int* __restrict__ gbp, int ngb,
                             float* __restrict__ out) {
    if (threadIdx.x != 0 || blockIdx.x != 0) return;
    const float dist = fwdD[TOTCELLS - 1] * UNSCALE;   // unscale shape loss
    const float Utot = acc[0];
    const float scale = (Utot > 1e-8f) ? ((float)(MM < NN ? MM : NN) / fmaxf(Utot, 1e-8f)) : 1.0f;
    const float temporal = scale * acc[1];

    int gb[MAXSEG + 1];
    const int n = (ngb <= MAXSEG + 1) ? ngb : (MAXSEG + 1);
    for (int q = 0; q < n; ++q) gb[q] = gbp[q];

    int nint = 0;
    for (int q = 0; q < n; ++q) if (gb[q] > 0 && gb[q] < MM) nint++;
    const float boundary = (nint > 0) ? (scale * acc[2] / (float)nint) : 0.f;

    float order = 0.f;
    if (n > 2) {
        float pos[MAXSEG];
        int np = 0;
        for (int s = 0; s + 1 < n; ++s) {
            const int st = gb[s], en = gb[s + 1];
            if (st >= MM || en > MM || st >= en) continue;
            const float mass = fmaxf(scale * acc[3 + s], 1e-8f);
            pos[np++] = scale * acc[3 + MAXSEG + s] / mass;
        }
        for (int k = 1; k < np; ++k) order += fmaxf(pos[k - 1] - pos[k], 0.f);
        if (np > 1) order /= (float)(np - 1);
    }

    float cov = 0.f;
    const int nsteps = n - 1;
    if (nsteps > 0) {
        for (int s = 0; s < nsteps; ++s) {
            const int st = gb[s];
            int en = gb[s + 1]; if (en > MM) en = MM;
            if (st >= en) continue;
            cov += fmaxf((float)(en - st) * 0.5f - scale * acc[3 + s], 0.f);
        }
        cov /= (float)nsteps;
    }

    out[0] = 0.3f * dist + 0.2f * temporal + 0.2f * boundary + 0.15f * order + 0.15f * cov;
}

// ---------------------------------------------------------------------------
extern "C" void kernel_launch(void* const* d_in, const int* in_sizes, int n_in,
                              void* d_out, int out_size, void* d_ws, size_t ws_size,
                              hipStream_t stream) {
    const float* pred   = (const float*)d_in[0];   // (2048, 64)
    const float* target = (const float*)d_in[1];   // (2048, 64)
    const int*   gb     = (const int*)d_in[2];     // (9,)
    const int ngb = in_sizes[2];

    float* costD = (float*)d_ws;
    float* fwdD  = costD + TOTCELLS;
    float* bwdD  = fwdD + TOTCELLS;
    float* acc   = bwdD + TOTCELLS;                 // 64 floats (zeroed by cost_kernel)
    unsigned* flagsP = (unsigned*)(acc + 64);       // [2][4] producer progress (zeroed)
    float* gringP    = (float*)(flagsP + 2 * NWGD); // [2][3][GRING]

    cost_kernel<<<dim3(NN / 64, MM / 64), 256, 0, stream>>>(pred, target, costD, acc);
    dp_pipe<<<2 * NWGD, NWAVE * 64, 0, stream>>>(costD, fwdD, bwdD, flagsP, gringP);
    combine_kernel<<<NDIAG, 256, 0, stream>>>(fwdD, bwdD, gb, ngb, acc);
    final_kernel<<<1, 64, 0, stream>>>(acc, fwdD, gb, ngb, (float*)d_out);
}

// Round 10
// 1452.975 us; speedup vs baseline: 1.5508x; 1.2468x over previous
//
#include <hip/hip_runtime.h>

#define MM 2048
#define NN 2048
#define DD 64
#define NDIAG (MM + NN - 1)      /* 4095 cost-matrix anti-diagonals */
#define TOTCELLS (MM * NN)
#define MAXSEG 15

// ---- skewed-pipeline DP geometry (D2: 2 diagonals per wall-step) ----
#define NWGD   4                 /* workgroups per direction               */
#define NWAVE  4                 /* waves per WG (1 strip per wave)        */
#define STRIPROWS 128            /* rows per strip (2 per lane)            */
#define TPS    32                /* ticks (diagonals) per superstep        */
#define BT     16                /* ticks per register batch (2/superstep) */
#define NSUPER 152               /* 152*32 = 4864 >= 4094 + Og(15)=768 + 1 */
#define GRING  1024              /* global ring entries per WG boundary    */
#define LRING  256               /* LDS ring entries per strip boundary    */
// Strip g tick-skew: Og = 32g + 96*(g/4). Intra-WG lag 33 ticks: batch at
// B0 consumes values written <= B0-18, always before the last barrier.
// Inter-WG lag 129 ticks -> producer flush superstep <= m-4; poll need=m-3.
// S_use(g) = Og + 128g = 160g + 96*(g/4); consumer columns ec = t - S_use.

constexpr float K2      = 14.426950408889634f;   // log2(e)/gamma, gamma=0.1
constexpr float INF_K   = 1.0e10f * 14.426950408889634f;
constexpr float UNSCALE = 0.06931471805599453f;  // gamma*ln2 = 1/K2

// Packed anti-diagonal layout for a 2048x2048 matrix: diag d = i+j, 0..4094.
__device__ __forceinline__ int diag_off(int d) {
    return (d < NN) ? ((d * (d + 1)) >> 1)
                    : (TOTCELLS - (((NDIAG - d) * (NDIAG - d + 1)) >> 1));
}
__device__ __forceinline__ int diag_imin(int d) { return (d < NN) ? 0 : (d - (NN - 1)); }
__device__ __forceinline__ int diag_len(int d)  { return (d < NN) ? (d + 1) : (NDIAG - d); }

__device__ __forceinline__ float fexp2(float x) { return __builtin_amdgcn_exp2f(x); }
__device__ __forceinline__ float flog2(float x) { return __builtin_amdgcn_logf(x); }

// rotate-up-by-1 across the wave via DPP wave_ror:1 (0x13C): lane l gets
// lane (l-1)&63's value at VALU latency. Lane 0's result is overridden.
__device__ __forceinline__ float rot_up1(float x) {
    int xi = __builtin_bit_cast(int, x);
    int r  = __builtin_amdgcn_update_dpp(xi, xi, 0x13C, 0xF, 0xF, true);
    return __builtin_bit_cast(float, r);
}

// softmin in the K2-scaled (log2) domain: m1 - log2(1 + 2^(m1-m2) + 2^(m1-m3))
__device__ __forceinline__ float softmin3k(float a, float b, float c) {
    const float m1 = fminf(fminf(a, b), c);
    const float m2 = __builtin_amdgcn_fmed3f(a, b, c);
    const float m3 = fmaxf(fmaxf(a, b), c);
    const float e  = 1.0f + fexp2(m1 - m2) + fexp2(m1 - m3);
    return m1 - flog2(e);
}

// ---------------------------------------------------------------------------
// cost[i,j] = K2 * sum_k (target[i,k]-pred[j,k])^2, packed diag layout.
// Block (0,0) also zeroes accumulators + pipeline flags (80 words).
// ---------------------------------------------------------------------------
__global__ __launch_bounds__(256) void cost_kernel(const float* __restrict__ pred,
                                                   const float* __restrict__ target,
                                                   float* __restrict__ costD,
                                                   float* __restrict__ acc) {
    __shared__ float Ts[64][65];
    __shared__ float Ps[64][65];
    const int tid = threadIdx.x;
    const int tx = tid & 15, ty = tid >> 4;
    const int i0 = blockIdx.y * 64;
    const int j0 = blockIdx.x * 64;

    if (blockIdx.x == 0 && blockIdx.y == 0 && tid < 80) ((unsigned*)acc)[tid] = 0u;

    #pragma unroll
    for (int rnd = 0; rnd < 4; ++rnd) {
        int f4i = tid + rnd * 256;
        int r  = f4i >> 4;
        int k4 = (f4i & 15) << 2;
        float4 tv = *reinterpret_cast<const float4*>(target + (size_t)(i0 + r) * DD + k4);
        Ts[r][k4 + 0] = tv.x; Ts[r][k4 + 1] = tv.y; Ts[r][k4 + 2] = tv.z; Ts[r][k4 + 3] = tv.w;
        float4 pv = *reinterpret_cast<const float4*>(pred + (size_t)(j0 + r) * DD + k4);
        Ps[k4 + 0][r] = pv.x; Ps[k4 + 1][r] = pv.y; Ps[k4 + 2][r] = pv.z; Ps[k4 + 3][r] = pv.w;
    }
    __syncthreads();

    float accv[4][4];
    #pragma unroll
    for (int a = 0; a < 4; ++a)
        #pragma unroll
        for (int b = 0; b < 4; ++b) accv[a][b] = 0.f;

    for (int k = 0; k < 64; ++k) {
        float ta[4], pb[4];
        #pragma unroll
        for (int a = 0; a < 4; ++a) ta[a] = Ts[ty + 16 * a][k];
        #pragma unroll
        for (int b = 0; b < 4; ++b) pb[b] = Ps[k][tx + 16 * b];
        #pragma unroll
        for (int a = 0; a < 4; ++a)
            #pragma unroll
            for (int b = 0; b < 4; ++b) {
                float d = ta[a] - pb[b];
                accv[a][b] = fmaf(d, d, accv[a][b]);
            }
    }
    #pragma unroll
    for (int a = 0; a < 4; ++a) {
        int i = i0 + ty + 16 * a;
        #pragma unroll
        for (int b = 0; b < 4; ++b) {
            int j = j0 + tx + 16 * b;
            int d = i + j;
            costD[diag_off(d) + (i - diag_imin(d))] = accv[a][b] * K2;
        }
    }
}

// ---------------------------------------------------------------------------
// Skewed register-resident soft-DTW, 2 diagonals (ticks) per wall-step.
// blocks 0-3: forward -> fwdD. blocks 4-7: backward as forward on the
// 180-rotated cost, OUTPUT ASCENDING in rotated layout -> bwdR (combine
// reads bwdR[TOT-1-x]). dir-1 staging reads costD with per-lane reversed
// quad sources (width-16 global_load_lds); the within-quad reversal is
// undone by a lane-constant XOR-2 address swizzle + pair swap at batch time.
// Per superstep (32 ticks): one staging phase (16 width-16 loads), two
// 16-tick register batches (cost ds_read_b64 + ring reads), then pure-reg
// tick bodies (DPP rotate + 2 softmin + 2 stores each), one barrier.
// ---------------------------------------------------------------------------
__global__ __launch_bounds__(256) void dp_pipe(const float* __restrict__ costD,
                                               float* __restrict__ fwdD,
                                               float* __restrict__ bwdR,
                                               unsigned* __restrict__ flagsP,
                                               float* __restrict__ gringP) {
    __shared__ float cls[2][NWAVE][TPS][STRIPROWS];   // 128 KB cost staging
    __shared__ float ring[NWAVE + 1][LRING];          // 5 KB boundary rings
    const int dir  = (int)blockIdx.x >> 2;
    const int wg   = (int)blockIdx.x & 3;
    const int tid  = threadIdx.x;
    const int wv   = tid >> 6;
    const int lane = tid & 63;
    const int g    = wg * NWAVE + wv;
    const int gu   = __builtin_amdgcn_readfirstlane(g);
    const int Og   = __builtin_amdgcn_readfirstlane(32 * g + 96 * (g >> 2));
    const int Suse = __builtin_amdgcn_readfirstlane(160 * g + 96 * (g >> 2));
    const int r0   = STRIPROWS * g + 2 * lane;
    float* __restrict__ outD = dir ? bwdR : fwdD;
    unsigned* pf = flagsP + dir * NWGD;
    float* grd   = gringP + (size_t)dir * 3 * GRING;
    const float* mring = ring[(wv == 0) ? NWAVE : (wv - 1)];
    // per-lane constants for staging / consumption
    const int lam4 = (lane & 31) << 2;                 // staged quad elem offset
    const int lamS = dir ? -lam4 : lam4;
    const int eoff = dir ? ((2 * lane) ^ 2) : (2 * lane);  // batch read elem offset

    int aS = r0;   // output flat addr of (diag dd, row r0); ascending both dirs

    // Stage 32 slices (ticks tb..tb+31, rot-rows 128g..128g+127) into
    // cls[bsel][wv]; 16 width-16 loads, 2 slices per instruction
    // (lanes 0-31 -> slice 2k, lanes 32-63 -> slice 2k+1).
    auto STAGE = [&](int tb, int bsel) {
        #pragma unroll
        for (int k = 0; k < 16; ++k) {
            const int dd0 = tb + 2 * k - Og;
            const int dc0 = (dd0 < 0) ? 0 : ((dd0 > NDIAG - 1) ? NDIAG - 1 : dd0);
            int b0 = diag_off(dc0) - diag_imin(dc0) + STRIPROWS * gu;
            const int dd1 = dd0 + 1;
            const int dc1 = (dd1 < 0) ? 0 : ((dd1 > NDIAG - 1) ? NDIAG - 1 : dd1);
            int b1 = diag_off(dc1) - diag_imin(dc1) + STRIPROWS * gu;
            if (dir) { b0 = TOTCELLS - 4 - b0; b1 = TOTCELLS - 4 - b1; }
            int src = ((lane < 32) ? b0 : b1) + lamS;
            src = (src < 0) ? 0 : ((src > TOTCELLS - 4) ? (TOTCELLS - 4) : src);
            __builtin_amdgcn_global_load_lds(
                (const __attribute__((address_space(1))) void*)(costD + src),
                (__attribute__((address_space(3))) void*)&cls[bsel][wv][2 * k][0],
                16, 0, 0);
        }
    };

    float Rk0 = INF_K, Rk0m1 = INF_K, Rk1 = INF_K;
    float dg0 = (g == 0 && lane == 0) ? 0.0f : INF_K;  // virtual R[0,0]=0

    STAGE(0, 0);
    __syncthreads();

    for (unsigned m = 0; m < NSUPER; ++m) {
        const int T0 = (int)(m * TPS);
        const int bsel = (int)(m & 1);

        // ---- inter-WG gather (wv0, wg>0): columns [c0g, c0g+63] -> ring[4]
        if (wv == 0 && wg > 0) {
            const int c0g = T0 - Suse;
            if (c0g + 63 >= 0 && c0g < NN) {
                const unsigned need = (m >= 3) ? (m - 3) : 0;
                unsigned guard = 0;
                while (__hip_atomic_load(&pf[wg - 1], __ATOMIC_ACQUIRE,
                                         __HIP_MEMORY_SCOPE_AGENT) < need &&
                       guard < (1u << 20)) { __builtin_amdgcn_s_sleep(8); ++guard; }
                const int c = c0g + lane;
                if (c >= 0 && c < NN)
                    ring[NWAVE][c & (LRING - 1)] =
                        __hip_atomic_load(&grd[(wg - 1) * GRING + (c & (GRING - 1))],
                                          __ATOMIC_RELAXED, __HIP_MEMORY_SCOPE_AGENT);
            }
        }

        // ---- issue staging for the NEXT superstep (drained at the barrier)
        if (m + 1 < NSUPER) STAGE(T0 + TPS, bsel ^ 1);

        // ---- two 16-tick batches: LDS->reg, then pure-register tick bodies
        #pragma unroll
        for (int h = 0; h < 2; ++h) {
            const int B0 = T0 + h * BT;
            float2 cb[BT];
            float  eb[BT];
            if (dir) {
                #pragma unroll
                for (int p = 0; p < BT; ++p) {
                    float2 r = *reinterpret_cast<const float2*>(
                        &cls[bsel][wv][h * BT + p][eoff]);
                    cb[p].x = r.y; cb[p].y = r.x;   // undo within-quad reversal
                }
            } else {
                #pragma unroll
                for (int p = 0; p < BT; ++p)
                    cb[p] = *reinterpret_cast<const float2*>(
                        &cls[bsel][wv][h * BT + p][eoff]);
            }
            if (g != 0) {
                #pragma unroll
                for (int p = 0; p < BT; ++p)
                    eb[p] = mring[((unsigned)(B0 + p - Suse)) & (LRING - 1)];
            } else {
                #pragma unroll
                for (int p = 0; p < BT; ++p) eb[p] = INF_K;
            }

            #pragma unroll
            for (int p = 0; p < BT; ++p) {
                const int t  = B0 + p;
                const int dd = t - Og;             // wave-uniform (SALU guard)
                if (dd >= 0 && dd < NDIAG) {
                    const int ec = t - Suse;       // boundary column this tick
                    float extv = INF_K;
                    if (g != 0 && ec >= 0 && ec < NN) extv = eb[p];
                    const float shr = rot_up1(Rk1);          // neighbor row r0-1
                    const float up0 = (lane == 0) ? extv : shr;
                    const float n0 = cb[p].x + softmin3k(dg0, up0, Rk0);
                    const float n1 = cb[p].y + softmin3k(Rk0m1, Rk0, Rk1);
                    const int c0 = dd - r0;
                    const bool v0 = (c0 >= 0) && (c0 < NN);
                    const bool v1 = (c0 >= 1) && (c0 <= NN);
                    Rk0m1 = Rk0;
                    if (v0) Rk0 = n0;
                    if (v1) Rk1 = n1;
                    dg0 = up0;
                    if (v0) outD[aS] = Rk0;
                    if (v1) outD[aS + 1] = Rk1;
                    const int pc = ec - (STRIPROWS - 1);   // publish last row
                    if (lane == 63 && pc >= 0 && pc < NN)
                        ring[wv][pc & (LRING - 1)] = Rk1;
                    const int ds = (dd + 1 < NDIAG - 1 - dd) ? (dd + 1) : (NDIAG - 1 - dd);
                    aS += ds;
                }
            }
        }
        __syncthreads();

        // ---- inter-WG flush (wv0): ring[3] -> global ring, then flag
        if (wv == 0 && wg < NWGD - 1) {
            const int Sp = 736 * wg + 480;          // S_use of strip 4wg+3
            const int cb0 = T0 - Sp - (STRIPROWS - 1);
            if (lane < TPS) {
                const int c = cb0 + lane;
                if (c >= 0 && c < NN)
                    __hip_atomic_store(&grd[wg * GRING + (c & (GRING - 1))],
                                       ring[NWAVE - 1][c & (LRING - 1)],
                                       __ATOMIC_RELAXED, __HIP_MEMORY_SCOPE_AGENT);
            }
            if (lane == 0)
                __hip_atomic_store(&pf[wg], m + 1, __ATOMIC_RELEASE,
                                   __HIP_MEMORY_SCOPE_AGENT);
        }
    }
}

// ---------------------------------------------------------------------------
// Per-cell alignment + linear reductions. a = exp2(-max(f + B - dist, 0)),
// where B comes from bwdR at the 180-rotated position TOT-1-flat.
// acc: [0]=total [1]=temporal [2]=boundary [3..17]=seg mass [18..32]=seg pos
// ---------------------------------------------------------------------------
__device__ __forceinline__ float wave_red(float v) {
    v += __shfl_xor(v, 32, 64);
    v += __shfl_xor(v, 16, 64);
    v += __shfl_xor(v, 8, 64);
    v += __shfl_xor(v, 4, 64);
    v += __shfl_xor(v, 2, 64);
    v += __shfl_xor(v, 1, 64);
    return v;
}

__global__ __launch_bounds__(256) void combine_kernel(const float* __restrict__ fwdD,
                                                      const float* __restrict__ bwdR,
                                                      const int* __restrict__ gbp, int ngb,
                                                      float* __restrict__ acc) {
    const int d = blockIdx.x;
    const int ofs = diag_off(d), imin = diag_imin(d), len = diag_len(d);
    const float dist = fwdD[TOTCELLS - 1];
    __shared__ float sseg[MAXSEG], ssegp[MAXSEG];
    __shared__ int sgb[MAXSEG + 1];
    const int tid = threadIdx.x;
    if (tid < MAXSEG) { sseg[tid] = 0.f; ssegp[tid] = 0.f; }
    if (tid < ngb && tid <= MAXSEG) sgb[tid] = gbp[tid];
    __syncthreads();

    float pT = 0.f, pTe = 0.f, pB = 0.f;
    const float invM1 = 1.f / (float)(MM - 1);
    const float invN1 = 1.f / (float)(NN - 1);
    const int nseg = ngb - 1;

    for (int x = tid; x < len; x += 256) {
        const int i0 = imin + x, j0 = d - i0;
        const float f = fwdD[ofs + x];
        const float b = bwdR[TOTCELLS - 1 - (ofs + x)];
        const float a = fexp2(-fmaxf(f + b - dist, 0.0f));
        const float jp = j0 * invN1, ip = i0 * invM1;
        pT += a;
        const float dt = ip - jp;
        pTe += a * dt * dt;
        int s = -1;
        for (int q = 0; q < nseg && q < MAXSEG; ++q)
            if (i0 >= sgb[q] && i0 < sgb[q + 1]) s = q;
        if (s >= 0) { atomicAdd(&sseg[s], a); atomicAdd(&ssegp[s], a * jp); }
        for (int q = 0; q < ngb && q <= MAXSEG; ++q) {
            const int bv = sgb[q];
            if (bv > 0 && bv < MM && i0 == bv) {
                const float dv = jp - (float)bv * invM1;
                pB += a * dv * dv;
            }
        }
    }
    pT = wave_red(pT); pTe = wave_red(pTe); pB = wave_red(pB);
    if ((tid & 63) == 0) {
        if (pT  != 0.f) atomicAdd(&acc[0], pT);
        if (pTe != 0.f) atomicAdd(&acc[1], pTe);
        if (pB  != 0.f) atomicAdd(&acc[2], pB);
    }
    __syncthreads();
    if (tid < nseg && tid < MAXSEG) {
        if (sseg[tid]  != 0.f) atomicAdd(&acc[3 + tid], sseg[tid]);
        if (ssegp[tid] != 0.f) atomicAdd(&acc[3 + MAXSEG + tid], ssegp[tid]);
    }
}

// ---------------------------------------------------------------------------
// Scalar epilogue replicating the reference's scale/order/coverage semantics.
// ---------------------------------------------------------------------------
__global__ void final_kernel(const float* __restrict__ acc,
                             const float* __restrict__ fwdD,
                             const int* __restrict__ gbp, int ngb,
                             float* __restrict__ out) {
    if (threadIdx.x != 0 || blockIdx.x != 0) return;
    const float dist = fwdD[TOTCELLS - 1] * UNSCALE;   // unscale shape loss
    const float Utot = acc[0];
    const float scale = (Utot > 1e-8f) ? ((float)(MM < NN ? MM : NN) / fmaxf(Utot, 1e-8f)) : 1.0f;
    const float temporal = scale * acc[1];

    int gb[MAXSEG + 1];
    const int n = (ngb <= MAXSEG + 1) ? ngb : (MAXSEG + 1);
    for (int q = 0; q < n; ++q) gb[q] = gbp[q];

    int nint = 0;
    for (int q = 0; q < n; ++q) if (gb[q] > 0 && gb[q] < MM) nint++;
    const float boundary = (nint > 0) ? (scale * acc[2] / (float)nint) : 0.f;

    float order = 0.f;
    if (n > 2) {
        float pos[MAXSEG];
        int np = 0;
        for (int s = 0; s + 1 < n; ++s) {
            const int st = gb[s], en = gb[s + 1];
            if (st >= MM || en > MM || st >= en) continue;
            const float mass = fmaxf(scale * acc[3 + s], 1e-8f);
            pos[np++] = scale * acc[3 + MAXSEG + s] / mass;
        }
        for (int k = 1; k < np; ++k) order += fmaxf(pos[k - 1] - pos[k], 0.f);
        if (np > 1) order /= (float)(np - 1);
    }

    float cov = 0.f;
    const int nsteps = n - 1;
    if (nsteps > 0) {
        for (int s = 0; s < nsteps; ++s) {
            const int st = gb[s];
            int en = gb[s + 1]; if (en > MM) en = MM;
            if (st >= en) continue;
            cov += fmaxf((float)(en - st) * 0.5f - scale * acc[3 + s], 0.f);
        }
        cov /= (float)nsteps;
    }

    out[0] = 0.3f * dist + 0.2f * temporal + 0.2f * boundary + 0.15f * order + 0.15f * cov;
}

// ---------------------------------------------------------------------------
extern "C" void kernel_launch(void* const* d_in, const int* in_sizes, int n_in,
                              void* d_out, int out_size, void* d_ws, size_t ws_size,
                              hipStream_t stream) {
    const float* pred   = (const float*)d_in[0];   // (2048, 64)
    const float* target = (const float*)d_in[1];   // (2048, 64)
    const int*   gb     = (const int*)d_in[2];     // (9,)
    const int ngb = in_sizes[2];

    float* costD = (float*)d_ws;
    float* fwdD  = costD + TOTCELLS;
    float* bwdR  = fwdD + TOTCELLS;                 // backward in rotated layout
    float* acc   = bwdR + TOTCELLS;                 // 64 floats (zeroed by cost_kernel)
    unsigned* flagsP = (unsigned*)(acc + 64);       // [2][4] producer progress (zeroed)
    float* gringP    = (float*)(flagsP + 2 * NWGD); // [2][3][GRING]

    cost_kernel<<<dim3(NN / 64, MM / 64), 256, 0, stream>>>(pred, target, costD, acc);
    dp_pipe<<<2 * NWGD, NWAVE * 64, 0, stream>>>(costD, fwdD, bwdR, flagsP, gringP);
    combine_kernel<<<NDIAG, 256, 0, stream>>>(fwdD, bwdR, gb, ngb, acc);
    final_kernel<<<1, 64, 0, stream>>>(acc, fwdD, gb, ngb, (float*)d_out);
}

// Round 11
// 1343.448 us; speedup vs baseline: 1.6772x; 1.0815x over previous
//
#include <hip/hip_runtime.h>

#define MM 2048
#define NN 2048
#define DD 64
#define NDIAG (MM + NN - 1)      /* 4095 cost-matrix anti-diagonals */
#define TOTCELLS (MM * NN)
#define MAXSEG 15

// ---- skewed-pipeline DP geometry ----
#define NWGD   4                 /* workgroups per direction               */
#define NWAVE  4                 /* waves per WG (1 strip per wave)        */
#define STRIPROWS 128            /* rows per strip (2 per lane)            */
#define TPS    32                /* ticks (diagonals) per superstep        */
#define BT     16                /* ticks per register batch (2/superstep) */
#define NSUPER 152               /* 152*32 = 4864 >= 4094 + Og(15)=768 + 1 */
#define GRING  1024              /* global ring entries per WG boundary    */
#define LRING  256               /* LDS ring entries per strip boundary    */
// Strip g tick-skew: Og = 32g + 96*(g/4). Intra-WG lag 33 ticks; inter-WG
// lag 129 ticks -> producer flush superstep <= m-4; poll need=m-3.
// S_use(g) = Og + 128g = 160g + 96*(g/4); consumer columns ec = t - S_use.

constexpr float K2      = 14.426950408889634f;   // log2(e)/gamma, gamma=0.1
constexpr float INF_K   = 1.0e10f * 14.426950408889634f;
constexpr float UNSCALE = 0.06931471805599453f;  // gamma*ln2 = 1/K2

// Packed anti-diagonal layout for a 2048x2048 matrix: diag d = i+j, 0..4094.
__device__ __forceinline__ int diag_off(int d) {
    return (d < NN) ? ((d * (d + 1)) >> 1)
                    : (TOTCELLS - (((NDIAG - d) * (NDIAG - d + 1)) >> 1));
}
__device__ __forceinline__ int diag_imin(int d) { return (d < NN) ? 0 : (d - (NN - 1)); }
__device__ __forceinline__ int diag_len(int d)  { return (d < NN) ? (d + 1) : (NDIAG - d); }

__device__ __forceinline__ float fexp2(float x) { return __builtin_amdgcn_exp2f(x); }
__device__ __forceinline__ float flog2(float x) { return __builtin_amdgcn_logf(x); }

// rotate-up-by-1 across the wave via DPP wave_ror:1 (0x13C): lane l gets
// lane (l-1)&63's value at VALU latency. Lane 0's result is overridden.
__device__ __forceinline__ float rot_up1(float x) {
    int xi = __builtin_bit_cast(int, x);
    int r  = __builtin_amdgcn_update_dpp(xi, xi, 0x13C, 0xF, 0xF, true);
    return __builtin_bit_cast(float, r);
}

// softmin in the K2-scaled (log2) domain: m1 - log2(1 + 2^(m1-m2) + 2^(m1-m3))
__device__ __forceinline__ float softmin3k(float a, float b, float c) {
    const float m1 = fminf(fminf(a, b), c);
    const float m2 = __builtin_amdgcn_fmed3f(a, b, c);
    const float m3 = fmaxf(fmaxf(a, b), c);
    const float e  = 1.0f + fexp2(m1 - m2) + fexp2(m1 - m3);
    return m1 - flog2(e);
}

// ---------------------------------------------------------------------------
// cost[i,j] = K2 * sum_k (target[i,k]-pred[j,k])^2, packed diag layout.
// Block (0,0) also zeroes accumulators + pipeline flags (80 words).
// ---------------------------------------------------------------------------
__global__ __launch_bounds__(256) void cost_kernel(const float* __restrict__ pred,
                                                   const float* __restrict__ target,
                                                   float* __restrict__ costD,
                                                   float* __restrict__ acc) {
    __shared__ float Ts[64][65];
    __shared__ float Ps[64][65];
    const int tid = threadIdx.x;
    const int tx = tid & 15, ty = tid >> 4;
    const int i0 = blockIdx.y * 64;
    const int j0 = blockIdx.x * 64;

    if (blockIdx.x == 0 && blockIdx.y == 0 && tid < 80) ((unsigned*)acc)[tid] = 0u;

    #pragma unroll
    for (int rnd = 0; rnd < 4; ++rnd) {
        int f4i = tid + rnd * 256;
        int r  = f4i >> 4;
        int k4 = (f4i & 15) << 2;
        float4 tv = *reinterpret_cast<const float4*>(target + (size_t)(i0 + r) * DD + k4);
        Ts[r][k4 + 0] = tv.x; Ts[r][k4 + 1] = tv.y; Ts[r][k4 + 2] = tv.z; Ts[r][k4 + 3] = tv.w;
        float4 pv = *reinterpret_cast<const float4*>(pred + (size_t)(j0 + r) * DD + k4);
        Ps[k4 + 0][r] = pv.x; Ps[k4 + 1][r] = pv.y; Ps[k4 + 2][r] = pv.z; Ps[k4 + 3][r] = pv.w;
    }
    __syncthreads();

    float accv[4][4];
    #pragma unroll
    for (int a = 0; a < 4; ++a)
        #pragma unroll
        for (int b = 0; b < 4; ++b) accv[a][b] = 0.f;

    for (int k = 0; k < 64; ++k) {
        float ta[4], pb[4];
        #pragma unroll
        for (int a = 0; a < 4; ++a) ta[a] = Ts[ty + 16 * a][k];
        #pragma unroll
        for (int b = 0; b < 4; ++b) pb[b] = Ps[k][tx + 16 * b];
        #pragma unroll
        for (int a = 0; a < 4; ++a)
            #pragma unroll
            for (int b = 0; b < 4; ++b) {
                float d = ta[a] - pb[b];
                accv[a][b] = fmaf(d, d, accv[a][b]);
            }
    }
    #pragma unroll
    for (int a = 0; a < 4; ++a) {
        int i = i0 + ty + 16 * a;
        #pragma unroll
        for (int b = 0; b < 4; ++b) {
            int j = j0 + tx + 16 * b;
            int d = i + j;
            costD[diag_off(d) + (i - diag_imin(d))] = accv[a][b] * K2;
        }
    }
}

// ---------------------------------------------------------------------------
// Skewed register-resident soft-DTW, 2 cells/lane/tick, batched LDS->reg.
// blocks 0-3: forward -> fwdD. blocks 4-7: backward on the 180-rotated cost,
// output ascending in rotated layout -> bwdR (combine reads bwdR[TOT-1-x]).
// R11: (1) raw s_barrier with COUNTED vmcnt(48) when the superstep is fully
// dd-active (the 64 tick stores are never read in-kernel; only the 16
// staging loads must retire, and they are older than the stores), vmcnt(0)
// fallback otherwise; (2) interior fast path per 16-tick batch (no masks);
// (3) whole-batch skip for inactive strips.
// ---------------------------------------------------------------------------
__global__ __launch_bounds__(256) void dp_pipe(const float* __restrict__ costD,
                                               float* __restrict__ fwdD,
                                               float* __restrict__ bwdR,
                                               unsigned* __restrict__ flagsP,
                                               float* __restrict__ gringP) {
    __shared__ float cls[2][NWAVE][TPS][STRIPROWS];   // 128 KB cost staging
    __shared__ float ring[NWAVE + 1][LRING];          // 5 KB boundary rings
    const int dir  = (int)blockIdx.x >> 2;
    const int wg   = (int)blockIdx.x & 3;
    const int tid  = threadIdx.x;
    const int wv   = tid >> 6;
    const int lane = tid & 63;
    const int g    = wg * NWAVE + wv;
    const int gu   = __builtin_amdgcn_readfirstlane(g);
    const int Og   = __builtin_amdgcn_readfirstlane(32 * g + 96 * (g >> 2));
    const int Suse = __builtin_amdgcn_readfirstlane(160 * g + 96 * (g >> 2));
    const int r0   = STRIPROWS * g + 2 * lane;
    float* __restrict__ outD = dir ? bwdR : fwdD;
    unsigned* pf = flagsP + dir * NWGD;
    float* grd   = gringP + (size_t)dir * 3 * GRING;
    const float* mring = ring[(wv == 0) ? NWAVE : (wv - 1)];
    const bool l0  = (lane == 0);
    const bool l63 = (lane == 63);
    const bool useExt = (g != 0);
    // per-lane constants for staging / consumption
    const int lam4 = (lane & 31) << 2;                 // staged quad elem offset
    const int lamS = dir ? -lam4 : lam4;
    const int eoff = dir ? ((2 * lane) ^ 2) : (2 * lane);  // batch read elem offset

    int aS = r0;   // output flat addr of (diag dd, row r0); ascending both dirs

    auto STAGE = [&](int tb, int bsel) {
        #pragma unroll
        for (int k = 0; k < 16; ++k) {
            const int dd0 = tb + 2 * k - Og;
            const int dc0 = (dd0 < 0) ? 0 : ((dd0 > NDIAG - 1) ? NDIAG - 1 : dd0);
            int b0 = diag_off(dc0) - diag_imin(dc0) + STRIPROWS * gu;
            const int dd1 = dd0 + 1;
            const int dc1 = (dd1 < 0) ? 0 : ((dd1 > NDIAG - 1) ? NDIAG - 1 : dd1);
            int b1 = diag_off(dc1) - diag_imin(dc1) + STRIPROWS * gu;
            if (dir) { b0 = TOTCELLS - 4 - b0; b1 = TOTCELLS - 4 - b1; }
            int src = ((lane < 32) ? b0 : b1) + lamS;
            src = (src < 0) ? 0 : ((src > TOTCELLS - 4) ? (TOTCELLS - 4) : src);
            __builtin_amdgcn_global_load_lds(
                (const __attribute__((address_space(1))) void*)(costD + src),
                (__attribute__((address_space(3))) void*)&cls[bsel][wv][2 * k][0],
                16, 0, 0);
        }
    };

    float Rk0 = INF_K, Rk0m1 = INF_K, Rk1 = INF_K;
    float dg0 = (g == 0 && lane == 0) ? 0.0f : INF_K;  // virtual R[0,0]=0

    STAGE(0, 0);
    __syncthreads();

    for (unsigned m = 0; m < NSUPER; ++m) {
        const int T0 = (int)(m * TPS);
        const int bsel = (int)(m & 1);

        // ---- inter-WG gather (wv0, wg>0): columns [c0g, c0g+63] -> ring[4]
        if (wv == 0 && wg > 0) {
            const int c0g = T0 - Suse;
            if (c0g + 63 >= 0 && c0g < NN) {
                const unsigned need = (m >= 3) ? (m - 3) : 0;
                unsigned guard = 0;
                while (__hip_atomic_load(&pf[wg - 1], __ATOMIC_ACQUIRE,
                                         __HIP_MEMORY_SCOPE_AGENT) < need &&
                       guard < (1u << 20)) { __builtin_amdgcn_s_sleep(8); ++guard; }
                const int c = c0g + lane;
                if (c >= 0 && c < NN)
                    ring[NWAVE][c & (LRING - 1)] =
                        __hip_atomic_load(&grd[(wg - 1) * GRING + (c & (GRING - 1))],
                                          __ATOMIC_RELAXED, __HIP_MEMORY_SCOPE_AGENT);
            }
        }

        // ---- issue staging for the NEXT superstep; pin its position in the
        // vmem stream (all tick stores must issue AFTER these loads).
        if (m + 1 < NSUPER) STAGE(T0 + TPS, bsel ^ 1);
        __builtin_amdgcn_sched_barrier(0);

        // fully-active superstep? (wave-uniform; decides barrier wait N)
        const bool fullS = (T0 - Og >= 0) && (T0 + TPS - 1 - Og <= NDIAG - 1);
        const int glo = STRIPROWS * gu;

        // ---- two 16-tick batches
        #pragma unroll
        for (int h = 0; h < 2; ++h) {
            const int B0 = T0 + h * BT;
            const int ddlo = B0 - Og, ddhi = B0 + BT - 1 - Og;
            if (ddhi < 0 || ddlo >= NDIAG) continue;      // strip inactive

            float2 cb[BT];
            float  eb[BT];
            if (dir) {
                #pragma unroll
                for (int p = 0; p < BT; ++p) {
                    float2 r = *reinterpret_cast<const float2*>(
                        &cls[bsel][wv][h * BT + p][eoff]);
                    cb[p].x = r.y; cb[p].y = r.x;   // undo within-quad reversal
                }
            } else {
                #pragma unroll
                for (int p = 0; p < BT; ++p)
                    cb[p] = *reinterpret_cast<const float2*>(
                        &cls[bsel][wv][h * BT + p][eoff]);
            }
            if (useExt) {
                #pragma unroll
                for (int p = 0; p < BT; ++p)
                    eb[p] = mring[((unsigned)(B0 + p - Suse)) & (LRING - 1)];
            } else {
                #pragma unroll
                for (int p = 0; p < BT; ++p) eb[p] = INF_K;
            }

            const bool fast = (ddlo >= glo + STRIPROWS) && (ddhi <= glo + NN - 1);
            if (fast) {
                // ---- interior: no bounds masks, unconditional stores ----
                #pragma unroll
                for (int p = 0; p < BT; ++p) {
                    const int t  = B0 + p;
                    const int dd = t - Og;
                    const float shr = rot_up1(Rk1);
                    const float up0 = l0 ? eb[p] : shr;
                    const float n0 = cb[p].x + softmin3k(dg0, up0, Rk0);
                    const float n1 = cb[p].y + softmin3k(Rk0m1, Rk0, Rk1);
                    Rk0m1 = Rk0; Rk0 = n0; Rk1 = n1; dg0 = up0;
                    outD[aS] = n0;
                    outD[aS + 1] = n1;
                    if (l63) ring[wv][(t - Suse - (STRIPROWS - 1)) & (LRING - 1)] = n1;
                    aS += (dd + 1 < NDIAG - 1 - dd) ? (dd + 1) : (NDIAG - 1 - dd);
                }
            } else {
                // ---- general path (edges) ----
                #pragma unroll
                for (int p = 0; p < BT; ++p) {
                    const int t  = B0 + p;
                    const int dd = t - Og;
                    if (dd >= 0 && dd < NDIAG) {
                        const int ec = t - Suse;
                        float extv = INF_K;
                        if (useExt && ec >= 0 && ec < NN) extv = eb[p];
                        const float shr = rot_up1(Rk1);
                        const float up0 = l0 ? extv : shr;
                        const float n0 = cb[p].x + softmin3k(dg0, up0, Rk0);
                        const float n1 = cb[p].y + softmin3k(Rk0m1, Rk0, Rk1);
                        const int c0 = dd - r0;
                        const bool v0 = (c0 >= 0) && (c0 < NN);
                        const bool v1 = (c0 >= 1) && (c0 <= NN);
                        Rk0m1 = Rk0;
                        if (v0) Rk0 = n0;
                        if (v1) Rk1 = n1;
                        dg0 = up0;
                        if (v0) outD[aS] = Rk0;
                        if (v1) outD[aS + 1] = Rk1;
                        const int pc = ec - (STRIPROWS - 1);
                        if (l63 && pc >= 0 && pc < NN)
                            ring[wv][pc & (LRING - 1)] = Rk1;
                        aS += (dd + 1 < NDIAG - 1 - dd) ? (dd + 1) : (NDIAG - 1 - dd);
                    }
                }
            }
        }

        // ---- barrier: counted vmcnt when safe (64 stores follow the 16
        // staging loads -> outstanding<=48 implies loads retired); the
        // stores themselves are never read in-kernel and may stay in flight.
        if (fullS) {
            asm volatile("s_waitcnt vmcnt(48) lgkmcnt(0)" ::: "memory");
        } else {
            asm volatile("s_waitcnt vmcnt(0) lgkmcnt(0)" ::: "memory");
        }
        __builtin_amdgcn_sched_barrier(0);
        __builtin_amdgcn_s_barrier();

        // ---- inter-WG flush (wv0): ring[3] -> global ring, then flag
        if (wv == 0 && wg < NWGD - 1) {
            const int Sp = 736 * wg + 480;          // S_use of strip 4wg+3
            const int cb0 = T0 - Sp - (STRIPROWS - 1);
            if (lane < TPS) {
                const int c = cb0 + lane;
                if (c >= 0 && c < NN)
                    __hip_atomic_store(&grd[wg * GRING + (c & (GRING - 1))],
                                       ring[NWAVE - 1][c & (LRING - 1)],
                                       __ATOMIC_RELAXED, __HIP_MEMORY_SCOPE_AGENT);
            }
            if (lane == 0)
                __hip_atomic_store(&pf[wg], m + 1, __ATOMIC_RELEASE,
                                   __HIP_MEMORY_SCOPE_AGENT);
        }
    }
}

// ---------------------------------------------------------------------------
// Per-cell alignment + linear reductions. a = exp2(-max(f + B - dist, 0)),
// B from bwdR at the 180-rotated position. Per-row LDS LUTs replace the
// per-cell segment search and boundary loop.
// acc: [0]=total [1]=temporal [2]=boundary [3..17]=seg mass [18..32]=seg pos
// ---------------------------------------------------------------------------
__device__ __forceinline__ float wave_red(float v) {
    v += __shfl_xor(v, 32, 64);
    v += __shfl_xor(v, 16, 64);
    v += __shfl_xor(v, 8, 64);
    v += __shfl_xor(v, 4, 64);
    v += __shfl_xor(v, 2, 64);
    v += __shfl_xor(v, 1, 64);
    return v;
}

__global__ __launch_bounds__(256) void combine_kernel(const float* __restrict__ fwdD,
                                                      const float* __restrict__ bwdR,
                                                      const int* __restrict__ gbp, int ngb,
                                                      float* __restrict__ acc) {
    const int d = blockIdx.x;
    const int ofs = diag_off(d), imin = diag_imin(d), len = diag_len(d);
    const float dist = fwdD[TOTCELLS - 1];
    __shared__ float sseg[MAXSEG], ssegp[MAXSEG];
    __shared__ int sgb[MAXSEG + 1];
    __shared__ signed char slut[MM];
    __shared__ signed char bflag[MM];
    const int tid = threadIdx.x;
    if (tid < MAXSEG) { sseg[tid] = 0.f; ssegp[tid] = 0.f; }
    if (tid < ngb && tid <= MAXSEG) sgb[tid] = gbp[tid];
    __syncthreads();

    const int nseg = ngb - 1;
    for (int r = tid; r < MM; r += 256) {
        int sres = -1;
        for (int q = 0; q < nseg && q < MAXSEG; ++q)
            if (r >= sgb[q] && r < sgb[q + 1]) sres = q;
        slut[r] = (signed char)sres;
        int bf = 0;
        for (int q = 0; q < ngb && q <= MAXSEG; ++q)
            if (sgb[q] == r && r > 0 && r < MM) bf = 1;
        bflag[r] = (signed char)bf;
    }
    __syncthreads();

    float pT = 0.f, pTe = 0.f, pB = 0.f;
    const float invM1 = 1.f / (float)(MM - 1);
    const float invN1 = 1.f / (float)(NN - 1);

    for (int x = tid; x < len; x += 256) {
        const int i0 = imin + x, j0 = d - i0;
        const float f = fwdD[ofs + x];
        const float b = bwdR[TOTCELLS - 1 - (ofs + x)];
        const float a = fexp2(-fmaxf(f + b - dist, 0.0f));
        const float jp = j0 * invN1, ip = i0 * invM1;
        pT += a;
        const float dt = ip - jp;
        pTe += a * dt * dt;
        const int s = slut[i0];
        if (s >= 0) { atomicAdd(&sseg[s], a); atomicAdd(&ssegp[s], a * jp); }
        if (bflag[i0]) {
            const float dv = jp - (float)i0 * invM1;
            pB += a * dv * dv;
        }
    }
    pT = wave_red(pT); pTe = wave_red(pTe); pB = wave_red(pB);
    if ((tid & 63) == 0) {
        if (pT  != 0.f) atomicAdd(&acc[0], pT);
        if (pTe != 0.f) atomicAdd(&acc[1], pTe);
        if (pB  != 0.f) atomicAdd(&acc[2], pB);
    }
    __syncthreads();
    if (tid < nseg && tid < MAXSEG) {
        if (sseg[tid]  != 0.f) atomicAdd(&acc[3 + tid], sseg[tid]);
        if (ssegp[tid] != 0.f) atomicAdd(&acc[3 + MAXSEG + tid], ssegp[tid]);
    }
}

// ---------------------------------------------------------------------------
// Scalar epilogue replicating the reference's scale/order/coverage semantics.
// ---------------------------------------------------------------------------
__global__ void final_kernel(const float* __restrict__ acc,
                             const float* __restrict__ fwdD,
                             const int* __restrict__ gbp, int ngb,
                             float* __restrict__ out) {
    if (threadIdx.x != 0 || blockIdx.x != 0) return;
    const float dist = fwdD[TOTCELLS - 1] * UNSCALE;   // unscale shape loss
    const float Utot = acc[0];
    const float scale = (Utot > 1e-8f) ? ((float)(MM < NN ? MM : NN) / fmaxf(Utot, 1e-8f)) : 1.0f;
    const float temporal = scale * acc[1];

    int gb[MAXSEG + 1];
    const int n = (ngb <= MAXSEG + 1) ? ngb : (MAXSEG + 1);
    for (int q = 0; q < n; ++q) gb[q] = gbp[q];

    int nint = 0;
    for (int q = 0; q < n; ++q) if (gb[q] > 0 && gb[q] < MM) nint++;
    const float boundary = (nint > 0) ? (scale * acc[2] / (float)nint) : 0.f;

    float order = 0.f;
    if (n > 2) {
        float pos[MAXSEG];
        int np = 0;
        for (int s = 0; s + 1 < n; ++s) {
            const int st = gb[s], en = gb[s + 1];
            if (st >= MM || en > MM || st >= en) continue;
            const float mass = fmaxf(scale * acc[3 + s], 1e-8f);
            pos[np++] = scale * acc[3 + MAXSEG + s] / mass;
        }
        for (int k = 1; k < np; ++k) order += fmaxf(pos[k - 1] - pos[k], 0.f);
        if (np > 1) order /= (float)(np - 1);
    }

    float cov = 0.f;
    const int nsteps = n - 1;
    if (nsteps > 0) {
        for (int s = 0; s < nsteps; ++s) {
            const int st = gb[s];
            int en = gb[s + 1]; if (en > MM) en = MM;
            if (st >= en) continue;
            cov += fmaxf((float)(en - st) * 0.5f - scale * acc[3 + s], 0.f);
        }
        cov /= (float)nsteps;
    }

    out[0] = 0.3f * dist + 0.2f * temporal + 0.2f * boundary + 0.15f * order + 0.15f * cov;
}

// ---------------------------------------------------------------------------
extern "C" void kernel_launch(void* const* d_in, const int* in_sizes, int n_in,
                              void* d_out, int out_size, void* d_ws, size_t ws_size,
                              hipStream_t stream) {
    const float* pred   = (const float*)d_in[0];   // (2048, 64)
    const float* target = (const float*)d_in[1];   // (2048, 64)
    const int*   gb     = (const int*)d_in[2];     // (9,)
    const int ngb = in_sizes[2];

    float* costD = (float*)d_ws;
    float* fwdD  = costD + TOTCELLS;
    float* bwdR  = fwdD + TOTCELLS;                 // backward in rotated layout
    float* acc   = bwdR + TOTCELLS;                 // 64 floats (zeroed by cost_kernel)
    unsigned* flagsP = (unsigned*)(acc + 64);       // [2][4] producer progress (zeroed)
    float* gringP    = (float*)(flagsP + 2 * NWGD); // [2][3][GRING]

    cost_kernel<<<dim3(NN / 64, MM / 64), 256, 0, stream>>>(pred, target, costD, acc);
    dp_pipe<<<2 * NWGD, NWAVE * 64, 0, stream>>>(costD, fwdD, bwdR, flagsP, gringP);
    combine_kernel<<<NDIAG, 256, 0, stream>>>(fwdD, bwdR, gb, ngb, acc);
    final_kernel<<<1, 64, 0, stream>>>(acc, fwdD, gb, ngb, (float*)d_out);
}